// Round 1
// baseline (354.445 us; speedup 1.0000x reference)
//
#include <hip/hip_runtime.h>
#include <math.h>

#define NN 100000          // nodes
#define NE 1600000         // edges
#define KDIM 128           // in_dim
#define ODIM 64            // out_dim
#define SCAN_B 512
#define NBLK ((NN + SCAN_B - 1) / SCAN_B)   // 196

// ---------------- Kernel A: h = x @ W^T, fused s_src = h@a_src, s_dst = h@a_dst ----
// 64-node tile, 256 threads as 16x16, each thread 4 nodes x 4 outs (strided by 16).
// LDS: x-tile and W both 64x128 f32, XOR-swizzled at float4 granularity to kill
// bank conflicts (unswizzled ws read would be 16-way).
__global__ __launch_bounds__(256, 2) void k_h(
    const float* __restrict__ x, const float* __restrict__ W,
    const float* __restrict__ a_src, const float* __restrict__ a_dst,
    float* __restrict__ h, float* __restrict__ ssrc, float* __restrict__ sdst)
{
  __shared__ float4 xs4[64 * 32];
  __shared__ float4 ws4[64 * 32];
  const int tid = threadIdx.x;
  const int ty = tid >> 4;   // 0..15 -> node row group
  const int tx = tid & 15;   // 0..15 -> out col group
  const int base = blockIdx.x * 64;

  const float4* x4 = (const float4*)x;
  const float4* W4 = (const float4*)W;
#pragma unroll
  for (int q = 0; q < 8; ++q) {
    int f = q * 256 + tid;            // 0..2047 float4s
    int row = f >> 5, c4 = f & 31;
    int sw = row * 32 + (c4 ^ (row & 7));
    ws4[sw] = W4[f];
    int node = base + row;
    float4 xv = make_float4(0.f, 0.f, 0.f, 0.f);
    if (node < NN) xv = x4[node * 32 + c4];
    xs4[sw] = xv;
  }
  __syncthreads();

  float acc[4][4];
#pragma unroll
  for (int i = 0; i < 4; ++i)
#pragma unroll
    for (int j = 0; j < 4; ++j) acc[i][j] = 0.f;

  const int axor = ty & 7, bxor = tx & 7;
  int arow[4], brow[4];
#pragma unroll
  for (int i = 0; i < 4; ++i) { arow[i] = (ty + 16 * i) * 32; brow[i] = (tx + 16 * i) * 32; }

#pragma unroll 8
  for (int k4 = 0; k4 < 32; ++k4) {
    float4 a4[4], b4[4];
#pragma unroll
    for (int i = 0; i < 4; ++i) a4[i] = xs4[arow[i] + (k4 ^ axor)];
#pragma unroll
    for (int j = 0; j < 4; ++j) b4[j] = ws4[brow[j] + (k4 ^ bxor)];
#pragma unroll
    for (int i = 0; i < 4; ++i)
#pragma unroll
      for (int j = 0; j < 4; ++j)
        acc[i][j] += a4[i].x * b4[j].x + a4[i].y * b4[j].y
                   + a4[i].z * b4[j].z + a4[i].w * b4[j].w;
  }

  // fused attention-logit tables: reduce over the 16 tx lanes (lane bits 0..3)
  float as[4], ad[4];
#pragma unroll
  for (int j = 0; j < 4; ++j) { as[j] = a_src[tx + 16 * j]; ad[j] = a_dst[tx + 16 * j]; }
#pragma unroll
  for (int i = 0; i < 4; ++i) {
    float ps = acc[i][0] * as[0] + acc[i][1] * as[1] + acc[i][2] * as[2] + acc[i][3] * as[3];
    float pd = acc[i][0] * ad[0] + acc[i][1] * ad[1] + acc[i][2] * ad[2] + acc[i][3] * ad[3];
#pragma unroll
    for (int m = 1; m < 16; m <<= 1) { ps += __shfl_xor(ps, m); pd += __shfl_xor(pd, m); }
    int node = base + ty + 16 * i;
    if (tx == 0 && node < NN) { ssrc[node] = ps; sdst[node] = pd; }
  }
  // h writeback
#pragma unroll
  for (int i = 0; i < 4; ++i) {
    int node = base + ty + 16 * i;
    if (node < NN) {
#pragma unroll
      for (int j = 0; j < 4; ++j) h[node * 64 + tx + 16 * j] = acc[i][j];
    }
  }
}

// ---------------- Kernel B: in-degree histogram ----------------
__global__ void k_count(const int* __restrict__ ei, int* __restrict__ counts)
{
  int e = blockIdx.x * blockDim.x + threadIdx.x;
  if (e < NE) atomicAdd(&counts[ei[NE + e]], 1);
}

// ---------------- Scan (3 kernels): exclusive prefix of counts -> offsets,cursor ---
__global__ void k_scan1(const int* __restrict__ counts, int* __restrict__ partials)
{
  __shared__ int sm[256];
  int b = blockIdx.x, t = threadIdx.x;
  int i0 = b * SCAN_B + t;
  int v = 0;
  if (i0 < NN) v = counts[i0];
  if (i0 + 256 < NN && (i0 + 256) < (b + 1) * SCAN_B) v += counts[i0 + 256];
  sm[t] = v;
  __syncthreads();
  for (int s = 128; s > 0; s >>= 1) { if (t < s) sm[t] += sm[t + s]; __syncthreads(); }
  if (t == 0) partials[b] = sm[0];
}

__global__ void k_scan2(int* __restrict__ partials, int* __restrict__ offsets)
{
  __shared__ int sm[256];
  int t = threadIdx.x;
  int v = (t < NBLK) ? partials[t] : 0;
  sm[t] = v;
  __syncthreads();
  for (int off = 1; off < 256; off <<= 1) {
    int u = (t >= off) ? sm[t - off] : 0;
    __syncthreads();
    sm[t] += u;
    __syncthreads();
  }
  if (t < NBLK) partials[t] = sm[t] - v;    // exclusive
  if (t == 0) offsets[NN] = sm[255];        // total = NE
}

__global__ void k_scan3(const int* __restrict__ counts, const int* __restrict__ partials,
                        int* __restrict__ offsets, int* __restrict__ cursor)
{
  __shared__ int sm[SCAN_B];
  int b = blockIdx.x, t = threadIdx.x;
  int i = b * SCAN_B + t;
  int v = (i < NN) ? counts[i] : 0;
  sm[t] = v;
  __syncthreads();
  for (int off = 1; off < SCAN_B; off <<= 1) {
    int u = (t >= off) ? sm[t - off] : 0;
    __syncthreads();
    sm[t] += u;
    __syncthreads();
  }
  if (i < NN) {
    int excl = partials[b] + sm[t] - v;
    offsets[i] = excl;
    cursor[i] = excl;
  }
}

// ---------------- Kernel E: scatter edges into CSR order, computing alpha_num ------
__global__ void k_scatter(const int* __restrict__ ei,
                          const float* __restrict__ ssrc, const float* __restrict__ sdst,
                          int* __restrict__ cursor,
                          int* __restrict__ csr_src, float* __restrict__ csr_a)
{
  int e = blockIdx.x * blockDim.x + threadIdx.x;
  if (e >= NE) return;
  int src = ei[e];
  int dst = ei[NE + e];
  int pos = atomicAdd(&cursor[dst], 1);
  float v = ssrc[src] + sdst[dst];
  v = (v >= 0.f) ? v : 0.2f * v;           // LeakyReLU(0.2)
  v = fminf(fmaxf(v, -10.f), 10.f);        // clip
  v = __expf(v);
  csr_src[pos] = src;
  csr_a[pos] = v;
}

// ---------------- Kernel F: atomic-free aggregation, wave per dst node -------------
__global__ __launch_bounds__(256) void k_agg(const int* __restrict__ offsets,
                                             const int* __restrict__ csr_src,
                                             const float* __restrict__ csr_a,
                                             const float* __restrict__ h,
                                             float* __restrict__ out)
{
  int wave = (int)((blockIdx.x * blockDim.x + threadIdx.x) >> 6);
  int lane = threadIdx.x & 63;
  if (wave >= NN) return;
  int beg = offsets[wave];
  int end = offsets[wave + 1];
  float acc = 0.f, denom = 0.f;
  for (int j = beg; j < end; ++j) {
    int s = csr_src[j];
    float a = csr_a[j];
    denom += a;
    acc += a * h[s * 64 + lane];
  }
  out[wave * 64 + lane] = acc / (denom + 1e-9f);
}

extern "C" void kernel_launch(void* const* d_in, const int* in_sizes, int n_in,
                              void* d_out, int out_size, void* d_ws, size_t ws_size,
                              hipStream_t stream)
{
  const float* x     = (const float*)d_in[0];
  const int*   ei    = (const int*)d_in[1];
  const float* W     = (const float*)d_in[2];
  const float* a_src = (const float*)d_in[3];
  const float* a_dst = (const float*)d_in[4];
  float* out = (float*)d_out;

  char* p = (char*)d_ws;
  auto alloc = [&](size_t bytes) -> char* {
    char* r = p;
    p += (bytes + 255) & ~(size_t)255;
    return r;
  };
  float* h       = (float*)alloc((size_t)NN * 64 * 4);
  float* ssrc    = (float*)alloc((size_t)NN * 4);
  float* sdst    = (float*)alloc((size_t)NN * 4);
  int*   counts  = (int*)alloc((size_t)NN * 4);
  int*   offsets = (int*)alloc((size_t)(NN + 1) * 4);
  int*   cursor  = (int*)alloc((size_t)NN * 4);
  int*   partials= (int*)alloc(256 * 4);
  int*   csr_src = (int*)alloc((size_t)NE * 4);
  float* csr_a   = (float*)alloc((size_t)NE * 4);

  hipMemsetAsync(counts, 0, (size_t)NN * 4, stream);
  k_h<<<(NN + 63) / 64, 256, 0, stream>>>(x, W, a_src, a_dst, h, ssrc, sdst);
  k_count<<<(NE + 255) / 256, 256, 0, stream>>>(ei, counts);
  k_scan1<<<NBLK, 256, 0, stream>>>(counts, partials);
  k_scan2<<<1, 256, 0, stream>>>(partials, offsets);
  k_scan3<<<NBLK, SCAN_B, 0, stream>>>(counts, partials, offsets, cursor);
  k_scatter<<<(NE + 255) / 256, 256, 0, stream>>>(ei, ssrc, sdst, cursor, csr_src, csr_a);
  k_agg<<<((size_t)NN * 64 + 255) / 256, 256, 0, stream>>>(offsets, csr_src, csr_a, h, out);
}

// Round 2
// 284.519 us; speedup vs baseline: 1.2458x; 1.2458x over previous
//
#include <hip/hip_runtime.h>
#include <math.h>

#define NN 100000          // nodes
#define NE 1600000         // edges
#define KDIM 128           // in_dim
#define ODIM 64            // out_dim
#define SCAN_B 512
#define NBLK ((NN + SCAN_B - 1) / SCAN_B)   // 196

typedef unsigned int uint;
typedef unsigned short ushort;

static __device__ __forceinline__ ushort f2bf(float f) {
  uint u = __float_as_uint(f);
  uint r = (u + 0x7fffu + ((u >> 16) & 1u)) >> 16;   // RNE
  return (ushort)r;
}
static __device__ __forceinline__ float bf2f(ushort v) {
  return __uint_as_float((uint)v << 16);
}

// ---------------- Kernel A: h = x @ W^T (bf16 out), fused s_src/s_dst ----
// 64-node tile, 256 threads as 16x16, each thread 4 nodes x 4 outs (strided by 16).
// LDS XOR-swizzled at float4 granularity (unswizzled reads would be multi-way conflicts).
__global__ __launch_bounds__(256, 2) void k_h(
    const float* __restrict__ x, const float* __restrict__ W,
    const float* __restrict__ a_src, const float* __restrict__ a_dst,
    ushort* __restrict__ h16, float* __restrict__ ssrc, float* __restrict__ sdst)
{
  __shared__ float4 xs4[64 * 32];
  __shared__ float4 ws4[64 * 32];
  const int tid = threadIdx.x;
  const int ty = tid >> 4;   // node row group
  const int tx = tid & 15;   // out col group
  const int base = blockIdx.x * 64;

  const float4* x4 = (const float4*)x;
  const float4* W4 = (const float4*)W;
#pragma unroll
  for (int q = 0; q < 8; ++q) {
    int f = q * 256 + tid;            // 0..2047 float4s
    int row = f >> 5, c4 = f & 31;
    int sw = row * 32 + (c4 ^ (row & 7));
    ws4[sw] = W4[f];
    int node = base + row;
    float4 xv = make_float4(0.f, 0.f, 0.f, 0.f);
    if (node < NN) xv = x4[node * 32 + c4];
    xs4[sw] = xv;
  }
  __syncthreads();

  float acc[4][4];
#pragma unroll
  for (int i = 0; i < 4; ++i)
#pragma unroll
    for (int j = 0; j < 4; ++j) acc[i][j] = 0.f;

  const int axor = ty & 7, bxor = tx & 7;
  int arow[4], brow[4];
#pragma unroll
  for (int i = 0; i < 4; ++i) { arow[i] = (ty + 16 * i) * 32; brow[i] = (tx + 16 * i) * 32; }

#pragma unroll 8
  for (int k4 = 0; k4 < 32; ++k4) {
    float4 a4[4], b4[4];
#pragma unroll
    for (int i = 0; i < 4; ++i) a4[i] = xs4[arow[i] + (k4 ^ axor)];
#pragma unroll
    for (int j = 0; j < 4; ++j) b4[j] = ws4[brow[j] + (k4 ^ bxor)];
#pragma unroll
    for (int i = 0; i < 4; ++i)
#pragma unroll
      for (int j = 0; j < 4; ++j)
        acc[i][j] += a4[i].x * b4[j].x + a4[i].y * b4[j].y
                   + a4[i].z * b4[j].z + a4[i].w * b4[j].w;
  }

  // fused attention-logit tables: reduce over the 16 tx lanes
  float as[4], ad[4];
#pragma unroll
  for (int j = 0; j < 4; ++j) { as[j] = a_src[tx + 16 * j]; ad[j] = a_dst[tx + 16 * j]; }
#pragma unroll
  for (int i = 0; i < 4; ++i) {
    float ps = acc[i][0] * as[0] + acc[i][1] * as[1] + acc[i][2] * as[2] + acc[i][3] * as[3];
    float pd = acc[i][0] * ad[0] + acc[i][1] * ad[1] + acc[i][2] * ad[2] + acc[i][3] * ad[3];
#pragma unroll
    for (int m = 1; m < 16; m <<= 1) { ps += __shfl_xor(ps, m); pd += __shfl_xor(pd, m); }
    int node = base + ty + 16 * i;
    if (tx == 0 && node < NN) { ssrc[node] = ps; sdst[node] = pd; }
  }
  // h writeback (bf16)
#pragma unroll
  for (int i = 0; i < 4; ++i) {
    int node = base + ty + 16 * i;
    if (node < NN) {
#pragma unroll
      for (int j = 0; j < 4; ++j) h16[node * 64 + tx + 16 * j] = f2bf(acc[i][j]);
    }
  }
}

// ---------------- Kernel B: in-degree histogram ----------------
__global__ void k_count(const int* __restrict__ ei, int* __restrict__ counts)
{
  int e = blockIdx.x * blockDim.x + threadIdx.x;
  if (e < NE) atomicAdd(&counts[ei[NE + e]], 1);
}

// ---------------- Scan (3 kernels): exclusive prefix of counts -> offsets,cursor ---
__global__ void k_scan1(const int* __restrict__ counts, int* __restrict__ partials)
{
  __shared__ int sm[256];
  int b = blockIdx.x, t = threadIdx.x;
  int i0 = b * SCAN_B + t;
  int v = 0;
  if (i0 < NN) v = counts[i0];
  if (i0 + 256 < NN && (i0 + 256) < (b + 1) * SCAN_B) v += counts[i0 + 256];
  sm[t] = v;
  __syncthreads();
  for (int s = 128; s > 0; s >>= 1) { if (t < s) sm[t] += sm[t + s]; __syncthreads(); }
  if (t == 0) partials[b] = sm[0];
}

__global__ void k_scan2(int* __restrict__ partials, int* __restrict__ offsets)
{
  __shared__ int sm[256];
  int t = threadIdx.x;
  int v = (t < NBLK) ? partials[t] : 0;
  sm[t] = v;
  __syncthreads();
  for (int off = 1; off < 256; off <<= 1) {
    int u = (t >= off) ? sm[t - off] : 0;
    __syncthreads();
    sm[t] += u;
    __syncthreads();
  }
  if (t < NBLK) partials[t] = sm[t] - v;    // exclusive
  if (t == 0) offsets[NN] = sm[255];        // total = NE
}

__global__ void k_scan3(const int* __restrict__ counts, const int* __restrict__ partials,
                        int* __restrict__ offsets, int* __restrict__ cursor)
{
  __shared__ int sm[SCAN_B];
  int b = blockIdx.x, t = threadIdx.x;
  int i = b * SCAN_B + t;
  int v = (i < NN) ? counts[i] : 0;
  sm[t] = v;
  __syncthreads();
  for (int off = 1; off < SCAN_B; off <<= 1) {
    int u = (t >= off) ? sm[t - off] : 0;
    __syncthreads();
    sm[t] += u;
    __syncthreads();
  }
  if (i < NN) {
    int excl = partials[b] + sm[t] - v;
    offsets[i] = excl;
    cursor[i] = excl;
  }
}

// ---------------- Kernel E: scatter edges into CSR order (packed int2) ------
__global__ void k_scatter(const int* __restrict__ ei,
                          const float* __restrict__ ssrc, const float* __restrict__ sdst,
                          int* __restrict__ cursor, int2* __restrict__ csr)
{
  int e = blockIdx.x * blockDim.x + threadIdx.x;
  if (e >= NE) return;
  int src = ei[e];
  int dst = ei[NE + e];
  int pos = atomicAdd(&cursor[dst], 1);
  float v = ssrc[src] + sdst[dst];
  v = (v >= 0.f) ? v : 0.2f * v;           // LeakyReLU(0.2)
  v = fminf(fmaxf(v, -10.f), 10.f);        // clip
  v = __expf(v);
  csr[pos] = make_int2(src, __float_as_int(v));
}

// ---------------- Kernel F: atomic-free aggregation, wave per dst node -------------
// masked unroll-4: 4 independent bf16 gathers in flight, no serial tail.
__global__ __launch_bounds__(256) void k_agg(const int* __restrict__ offsets,
                                             const int2* __restrict__ csr,
                                             const ushort* __restrict__ h16,
                                             float* __restrict__ out)
{
  int wave = (int)((blockIdx.x * blockDim.x + threadIdx.x) >> 6);
  int lane = threadIdx.x & 63;
  if (wave >= NN) return;
  int beg = offsets[wave];
  int end = offsets[wave + 1];
  float acc = 0.f, den = 0.f;
  int last = end - 1;
  for (int j = beg; j < end; j += 4) {
    int2 e0 = csr[j];
    int2 e1 = csr[min(j + 1, last)];
    int2 e2 = csr[min(j + 2, last)];
    int2 e3 = csr[min(j + 3, last)];
    float a0 = __int_as_float(e0.y);
    float a1 = (j + 1 < end) ? __int_as_float(e1.y) : 0.f;
    float a2 = (j + 2 < end) ? __int_as_float(e2.y) : 0.f;
    float a3 = (j + 3 < end) ? __int_as_float(e3.y) : 0.f;
    float v0 = bf2f(h16[e0.x * 64 + lane]);
    float v1 = bf2f(h16[e1.x * 64 + lane]);
    float v2 = bf2f(h16[e2.x * 64 + lane]);
    float v3 = bf2f(h16[e3.x * 64 + lane]);
    den += (a0 + a1) + (a2 + a3);
    acc += a0 * v0 + a1 * v1 + a2 * v2 + a3 * v3;
  }
  out[wave * 64 + lane] = acc / (den + 1e-9f);
}

extern "C" void kernel_launch(void* const* d_in, const int* in_sizes, int n_in,
                              void* d_out, int out_size, void* d_ws, size_t ws_size,
                              hipStream_t stream)
{
  const float* x     = (const float*)d_in[0];
  const int*   ei    = (const int*)d_in[1];
  const float* W     = (const float*)d_in[2];
  const float* a_src = (const float*)d_in[3];
  const float* a_dst = (const float*)d_in[4];
  float* out = (float*)d_out;

  char* p = (char*)d_ws;
  auto alloc = [&](size_t bytes) -> char* {
    char* r = p;
    p += (bytes + 255) & ~(size_t)255;
    return r;
  };
  ushort* h16    = (ushort*)alloc((size_t)NN * 64 * 2);
  float* ssrc    = (float*)alloc((size_t)NN * 4);
  float* sdst    = (float*)alloc((size_t)NN * 4);
  int*   counts  = (int*)alloc((size_t)NN * 4);
  int*   offsets = (int*)alloc((size_t)(NN + 1) * 4);
  int*   cursor  = (int*)alloc((size_t)NN * 4);
  int*   partials= (int*)alloc(256 * 4);
  int2*  csr     = (int2*)alloc((size_t)NE * 8);

  hipMemsetAsync(counts, 0, (size_t)NN * 4, stream);
  k_h<<<(NN + 63) / 64, 256, 0, stream>>>(x, W, a_src, a_dst, h16, ssrc, sdst);
  k_count<<<(NE + 255) / 256, 256, 0, stream>>>(ei, counts);
  k_scan1<<<NBLK, 256, 0, stream>>>(counts, partials);
  k_scan2<<<1, 256, 0, stream>>>(partials, offsets);
  k_scan3<<<NBLK, SCAN_B, 0, stream>>>(counts, partials, offsets, cursor);
  k_scatter<<<(NE + 255) / 256, 256, 0, stream>>>(ei, ssrc, sdst, cursor, csr);
  k_agg<<<((size_t)NN * 64 + 255) / 256, 256, 0, stream>>>(offsets, csr, h16, out);
}